// Round 1
// baseline (3899.834 us; speedup 1.0000x reference)
//
#include <hip/hip_runtime.h>
#include <hip/hip_bf16.h>

#define HIDDEN 4096
#define INTER  11008
#define TOKENS 8192

typedef __bf16 bf16x8 __attribute__((ext_vector_type(8)));
typedef float  f32x4  __attribute__((ext_vector_type(4)));

typedef unsigned int as1_uint __attribute__((address_space(1)));
typedef unsigned int as3_uint __attribute__((address_space(3)));

// async global->LDS, 16B per lane; LDS dest is wave-uniform base + lane*16
__device__ __forceinline__ void gld_lds16(const void* g, void* l) {
    __builtin_amdgcn_global_load_lds((as1_uint*)g, (as3_uint*)l, 16, 0, 0);
}

__device__ __forceinline__ unsigned short f2bf_bits(float f) {
    union { float f; unsigned u; } c; c.f = f;
    unsigned u = c.u;
    u += 0x7fffu + ((u >> 16) & 1u);   // round-to-nearest-even
    return (unsigned short)(u >> 16);
}

__global__ __launch_bounds__(256) void cast_f32_bf16(const float4* __restrict__ in,
                                                     ushort4* __restrict__ out, long n4) {
    long i = (long)blockIdx.x * blockDim.x + threadIdx.x;
    long stride = (long)gridDim.x * blockDim.x;
    for (; i < n4; i += stride) {
        float4 v = in[i];
        ushort4 o;
        o.x = f2bf_bits(v.x); o.y = f2bf_bits(v.y);
        o.z = f2bf_bits(v.z); o.w = f2bf_bits(v.w);
        out[i] = o;
    }
}

// Fused gate/up GEMM + SiLU*mul epilogue.
// C_g = X @ Wg^T, C_u = X @ Wu^T  (X:[TOKENS][HIDDEN], W:[INTER][HIDDEN] row-major)
// H = silu(C_g) * C_u  stored bf16 [TOKENS][INTER]
// BM=128, BN=64, BK=32. 256 threads = 4 waves in 2x2; wave tile 64x32 (x2 outputs).
__global__ __launch_bounds__(256, 2)
void gemm_gateup(const __hip_bfloat16* __restrict__ X,
                 const __hip_bfloat16* __restrict__ Wg,
                 const __hip_bfloat16* __restrict__ Wu,
                 __hip_bfloat16* __restrict__ H) {
    __shared__ __attribute__((aligned(16))) __hip_bfloat16 sA[128 * 32];
    __shared__ __attribute__((aligned(16))) __hip_bfloat16 sG[64 * 32];
    __shared__ __attribute__((aligned(16))) __hip_bfloat16 sU[64 * 32];

    const int tid  = threadIdx.x;
    const int wave = tid >> 6;
    const int lane = tid & 63;
    const int m0 = blockIdx.y * 128;
    const int n0 = blockIdx.x * 64;

    const int wm = (wave >> 1) * 64;   // wave row offset in block tile
    const int wn = (wave & 1) * 32;    // wave col offset
    const int ml = lane & 15;
    const int k8 = (lane >> 4) * 8;

    // staging coords (row-major [rows][32] tile, thread t covers elements 8t..8t+7)
    const int srow0 = tid >> 2;                 // rows 0..63   (round 0)
    const int scol  = (tid & 3) * 8;
    const int srow1 = (tid + 256) >> 2;         // rows 64..127 (round 1, A only)

    f32x4 accG[4][2], accU[4][2];
#pragma unroll
    for (int i = 0; i < 4; i++)
#pragma unroll
        for (int j = 0; j < 2; j++) {
            accG[i][j] = f32x4{0.f, 0.f, 0.f, 0.f};
            accU[i][j] = f32x4{0.f, 0.f, 0.f, 0.f};
        }

    for (int k0 = 0; k0 < HIDDEN; k0 += 32) {
        // A tile: 128x32 (2 rounds)
        gld_lds16(X + (long)(m0 + srow0) * HIDDEN + k0 + scol, sA + (wave * 64) * 8);
        gld_lds16(X + (long)(m0 + srow1) * HIDDEN + k0 + scol, sA + (256 + wave * 64) * 8);
        // Wg / Wu tiles: 64x32 (1 round each)
        gld_lds16(Wg + (long)(n0 + srow0) * HIDDEN + k0 + scol, sG + (wave * 64) * 8);
        gld_lds16(Wu + (long)(n0 + srow0) * HIDDEN + k0 + scol, sU + (wave * 64) * 8);
        __syncthreads();

        bf16x8 aF[4], bG[2], bU[2];
#pragma unroll
        for (int i = 0; i < 4; i++)
            aF[i] = *(const bf16x8*)(sA + (wm + i * 16 + ml) * 32 + k8);
#pragma unroll
        for (int j = 0; j < 2; j++) {
            bG[j] = *(const bf16x8*)(sG + (wn + j * 16 + ml) * 32 + k8);
            bU[j] = *(const bf16x8*)(sU + (wn + j * 16 + ml) * 32 + k8);
        }
#pragma unroll
        for (int i = 0; i < 4; i++)
#pragma unroll
            for (int j = 0; j < 2; j++) {
                accG[i][j] = __builtin_amdgcn_mfma_f32_16x16x32_bf16(aF[i], bG[j], accG[i][j], 0, 0, 0);
                accU[i][j] = __builtin_amdgcn_mfma_f32_16x16x32_bf16(aF[i], bU[j], accU[i][j], 0, 0, 0);
            }
        __syncthreads();
    }

    // epilogue: h = silu(g)*u ; C/D layout: col=lane&15, row=(lane>>4)*4+reg
#pragma unroll
    for (int i = 0; i < 4; i++) {
#pragma unroll
        for (int j = 0; j < 2; j++) {
            long row0 = m0 + wm + i * 16 + (lane >> 4) * 4;
            int  col  = n0 + wn + j * 16 + ml;
#pragma unroll
            for (int r = 0; r < 4; r++) {
                float g = accG[i][j][r];
                float u = accU[i][j][r];
                float h = g / (1.f + __expf(-g)) * u;
                H[(row0 + r) * (long)INTER + col] = __float2bfloat16(h);
            }
        }
    }
}

// Down GEMM: O = H @ Wd^T  (H:[TOKENS][INTER] bf16, Wd:[HIDDEN][INTER] bf16, O fp32)
// m97 structure: BM=BN=128, BK=32, 4 waves each 64x64.
__global__ __launch_bounds__(256, 2)
void gemm_down(const __hip_bfloat16* __restrict__ A,
               const __hip_bfloat16* __restrict__ B,
               float* __restrict__ O) {
    __shared__ __attribute__((aligned(16))) __hip_bfloat16 sA[128 * 32];
    __shared__ __attribute__((aligned(16))) __hip_bfloat16 sB[128 * 32];

    const int tid  = threadIdx.x;
    const int wave = tid >> 6;
    const int lane = tid & 63;
    const int m0 = blockIdx.y * 128;
    const int n0 = blockIdx.x * 128;

    const int wm = (wave >> 1) * 64;
    const int wn = (wave & 1) * 64;
    const int ml = lane & 15;
    const int k8 = (lane >> 4) * 8;

    const int srow0 = tid >> 2;
    const int scol  = (tid & 3) * 8;
    const int srow1 = (tid + 256) >> 2;

    f32x4 acc[4][4];
#pragma unroll
    for (int i = 0; i < 4; i++)
#pragma unroll
        for (int j = 0; j < 4; j++) acc[i][j] = f32x4{0.f, 0.f, 0.f, 0.f};

    for (int k0 = 0; k0 < INTER; k0 += 32) {
        gld_lds16(A + (long)(m0 + srow0) * INTER + k0 + scol, sA + (wave * 64) * 8);
        gld_lds16(A + (long)(m0 + srow1) * INTER + k0 + scol, sA + (256 + wave * 64) * 8);
        gld_lds16(B + (long)(n0 + srow0) * INTER + k0 + scol, sB + (wave * 64) * 8);
        gld_lds16(B + (long)(n0 + srow1) * INTER + k0 + scol, sB + (256 + wave * 64) * 8);
        __syncthreads();

        bf16x8 aF[4], bF[4];
#pragma unroll
        for (int i = 0; i < 4; i++) {
            aF[i] = *(const bf16x8*)(sA + (wm + i * 16 + ml) * 32 + k8);
            bF[i] = *(const bf16x8*)(sB + (wn + i * 16 + ml) * 32 + k8);
        }
#pragma unroll
        for (int i = 0; i < 4; i++)
#pragma unroll
            for (int j = 0; j < 4; j++)
                acc[i][j] = __builtin_amdgcn_mfma_f32_16x16x32_bf16(aF[i], bF[j], acc[i][j], 0, 0, 0);
        __syncthreads();
    }

#pragma unroll
    for (int i = 0; i < 4; i++) {
#pragma unroll
        for (int j = 0; j < 4; j++) {
            long row0 = m0 + wm + i * 16 + (lane >> 4) * 4;
            int  col  = n0 + wn + j * 16 + ml;
#pragma unroll
            for (int r = 0; r < 4; r++)
                O[(row0 + r) * (long)HIDDEN + col] = acc[i][j][r];
        }
    }
}

extern "C" void kernel_launch(void* const* d_in, const int* in_sizes, int n_in,
                              void* d_out, int out_size, void* d_ws, size_t ws_size,
                              hipStream_t stream) {
    const float* x  = (const float*)d_in[0];   // [TOKENS][HIDDEN]
    const float* wg = (const float*)d_in[1];   // [INTER][HIDDEN]
    const float* wu = (const float*)d_in[2];   // [INTER][HIDDEN]
    const float* wd = (const float*)d_in[3];   // [HIDDEN][INTER]
    float* out = (float*)d_out;                // [TOKENS][HIDDEN]

    // workspace layout (peak 427.8 MB):
    //   [0, SZ_H)                         hidden bf16
    //   [SZ_H, SZ_H+SZ_X)                 x bf16
    //   [SZ_H+SZ_X, +SZ_W)                Wg bf16
    //   [SZ_H+SZ_X+SZ_W, +SZ_W)           Wu bf16
    //   Wd bf16 aliases [SZ_H, SZ_H+SZ_W) (x/Wg dead after gemm_gateup; stream-ordered)
    const size_t SZ_H = (size_t)TOKENS * INTER * 2;   // 180,355,072
    const size_t SZ_X = (size_t)TOKENS * HIDDEN * 2;  //  67,108,864
    const size_t SZ_W = (size_t)INTER * HIDDEN * 2;   //  90,177,536

    char* ws = (char*)d_ws;
    __hip_bfloat16* Hb  = (__hip_bfloat16*)(ws);
    __hip_bfloat16* Xb  = (__hip_bfloat16*)(ws + SZ_H);
    __hip_bfloat16* Wgb = (__hip_bfloat16*)(ws + SZ_H + SZ_X);
    __hip_bfloat16* Wub = (__hip_bfloat16*)(ws + SZ_H + SZ_X + SZ_W);
    __hip_bfloat16* Wdb = (__hip_bfloat16*)(ws + SZ_H);  // alias, used after gateup

    auto cast_launch = [&](const float* src, __hip_bfloat16* dst, long n) {
        long n4 = n >> 2;
        long b = (n4 + 255) / 256;
        if (b > 16384) b = 16384;
        cast_f32_bf16<<<(int)b, 256, 0, stream>>>((const float4*)src, (ushort4*)dst, n4);
    };

    cast_launch(x,  Xb,  (long)TOKENS * HIDDEN);
    cast_launch(wg, Wgb, (long)INTER * HIDDEN);
    cast_launch(wu, Wub, (long)INTER * HIDDEN);

    gemm_gateup<<<dim3(INTER / 64, TOKENS / 128), 256, 0, stream>>>(Xb, Wgb, Wub, Hb);

    cast_launch(wd, Wdb, (long)HIDDEN * INTER);

    gemm_down<<<dim3(HIDDEN / 128, TOKENS / 128), 256, 0, stream>>>(Hb, Wdb, out);
}